// Round 4
// baseline (3378.055 us; speedup 1.0000x reference)
//
#include <hip/hip_runtime.h>

using u16 = unsigned short;
using u32 = unsigned int;
using u64 = unsigned long long;
using bf16x8 = __attribute__((ext_vector_type(8))) short;
using f16x8  = __attribute__((ext_vector_type(8))) _Float16;
using f32x4  = __attribute__((ext_vector_type(4))) float;
using u32x4  = __attribute__((ext_vector_type(4))) unsigned int;

// ---------------- workspace layout (bytes) ----------------
static constexpr size_t XU_OFF = 0;
static constexpr size_t XU_BYTES = (size_t)512 * 64 * 4096 * 2;      // 256 MiB
static constexpr size_t XB_OFF = XU_OFF + XU_BYTES;
static constexpr size_t XB_BYTES = (size_t)64 * 512 * 1024 * 2;      // 64 MiB
static constexpr size_t UT_OFF = XB_OFF + XB_BYTES;
static constexpr size_t WT_BYTES = (size_t)4096 * 1024 * 2;          // 8 MiB
static constexpr size_t VT_OFF = UT_OFF + WT_BYTES;
static constexpr size_t BP_OFF = VT_OFF + WT_BYTES;
static constexpr size_t BP_BYTES = 4096 * 4;
// tagged h plane: [2 parity][4 group][16 row][1024 col] u16
// u16 = (fp16(h) & 0xFFFE) | phase-bit, phase = (t>>1)&1
static constexpr size_t HT_PLANE = (size_t)2 * 4 * 16 * 1024 * 2;    // 256 KiB
static constexpr size_t HHI_OFF = BP_OFF + BP_BYTES;
static constexpr size_t HT_HALF = HT_PLANE / 2;                      // one parity slot

__device__ __forceinline__ float bf2f(u32 u) {
    return __uint_as_float(u << 16);
}
__device__ __forceinline__ u16 f2bf(float f) {
    u32 u = __float_as_uint(f);
    u32 r = (u + 0x7FFFu + ((u >> 16) & 1u)) >> 16;
    return (u16)r;
}
__device__ __forceinline__ u16 f2h(float f) {
    _Float16 x = (_Float16)f;                     // RTN
    union { _Float16 h; u16 u; } cv;
    cv.h = x;
    return cv.u;
}

// fast gates: v_exp + v_rcp (err ~1e-7, far below bf16 pipeline noise)
__device__ __forceinline__ float fast_sigmoid(float x) {
    return __builtin_amdgcn_rcpf(1.f + __expf(-x));
}
__device__ __forceinline__ float fast_tanh(float x) {
    return 1.f - 2.f * __builtin_amdgcn_rcpf(1.f + __expf(2.f * x));
}

// 16B cache-bypassing load (full-64B-line MALL requests)
__device__ __forceinline__ u32x4 load16_uc(const u16* p) {
    u32x4 v;
    asm volatile("global_load_dwordx4 %0, %1, off sc0 sc1"
                 : "=v"(v)
                 : "v"(p));
    return v;
}

// ------------- x fp32 -> bf16 -------------
__global__ void cvt_x_kernel(const float4* __restrict__ x, uint2* __restrict__ xb) {
    int i = blockIdx.x * 256 + threadIdx.x;
#pragma unroll
    for (int k = 0; k < 8; ++k) {
        int idx = i + k * 1048576;
        float4 v = x[idx];
        uint2 o;
        o.x = (u32)f2bf(v.x) | ((u32)f2bf(v.y) << 16);
        o.y = (u32)f2bf(v.z) | ((u32)f2bf(v.w) << 16);
        xb[idx] = o;
    }
}

// ------------- repack: U fp32->bf16, V fp32->fp16; K-contiguous, gate-interleaved columns -------------
__global__ void repack_kernel(const float* U0, const float* U1, const float* U2, const float* U3,
                              const float* V0, const float* V1, const float* V2, const float* V3,
                              u16* UT, u16* VT) {
    __shared__ u16 tile[64][65];
    int bx  = blockIdx.x;
    int mat = bx >> 8;
    int rem = bx & 255;
    int tf = rem >> 4, th = rem & 15;
    int f0 = tf * 64, h0 = th * 64;
    const float* srcs[8] = {U0, U1, U2, U3, V0, V1, V2, V3};
    const float* s = srcs[mat];
    u16* d = (mat < 4) ? UT : VT;
    bool isU = (mat < 4);
    int g = mat & 3;
    int c = threadIdx.x & 63;
    int r = threadIdx.x >> 6;
#pragma unroll
    for (int i = 0; i < 16; ++i) {
        int fr = r + i * 4;
        float v = s[(size_t)(f0 + fr) * 1024 + h0 + c];
        tile[fr][c] = isU ? f2bf(v) : f2h(v);
    }
    __syncthreads();
#pragma unroll
    for (int i = 0; i < 16; ++i) {
        int hcl = r + i * 4;
        d[(size_t)((h0 + hcl) * 4 + g) * 1024 + f0 + c] = tile[c][hcl];
    }
}

// ------------- bias pack -------------
__global__ void bias_kernel(const float* b0, const float* b1, const float* b2, const float* b3,
                            float* bp) {
    int n = blockIdx.x * 256 + threadIdx.x;
    int g = n & 3, hc = n >> 2;
    const float* bs[4] = {b0, b1, b2, b3};
    bp[n] = bs[g][hc];
}

// ------------- xU GEMM (XCD-chunked swizzle; neutral but harmless) -------------
__global__ void __launch_bounds__(256) gemm_xu_kernel(const u16* __restrict__ xb,
                                                      const u16* __restrict__ UT,
                                                      const float* __restrict__ bp,
                                                      u16* __restrict__ xu) {
    int bx0 = blockIdx.x;
    int bx = (bx0 & 7) * 1024 + (bx0 >> 3);       // bijective (8192 % 8 == 0)
    int nt = bx & 31, mt = bx >> 5;
    int tid = threadIdx.x;
    int lane = tid & 63, wv = tid >> 6;
    int wm = wv & 1, wn = wv >> 1;
    int l15 = lane & 15, quad = lane >> 4;

    int arow0 = mt * 128 + wm * 64 + l15;
    int brow0 = nt * 128 + wn * 64 + l15;

    f32x4 acc[4][4];
#pragma unroll
    for (int i = 0; i < 4; ++i)
#pragma unroll
        for (int j = 0; j < 4; ++j) acc[i][j] = f32x4{0.f, 0.f, 0.f, 0.f};

    float biasv[4];
#pragma unroll
    for (int j = 0; j < 4; ++j) biasv[j] = bp[brow0 + 16 * j];

    const u16* abase = xb + (size_t)arow0 * 1024;
    const u16* bbase = UT + (size_t)brow0 * 1024;

#pragma unroll 2
    for (int kk = 0; kk < 32; ++kk) {
        int ko = kk * 32 + quad * 8;
        bf16x8 af[4], bfv[4];
#pragma unroll
        for (int i = 0; i < 4; ++i)
            af[i] = *(const bf16x8*)(abase + (size_t)i * 16 * 1024 + ko);
#pragma unroll
        for (int j = 0; j < 4; ++j)
            bfv[j] = *(const bf16x8*)(bbase + (size_t)j * 16 * 1024 + ko);
#pragma unroll
        for (int i = 0; i < 4; ++i)
#pragma unroll
            for (int j = 0; j < 4; ++j)
                acc[i][j] = __builtin_amdgcn_mfma_f32_16x16x32_bf16(af[i], bfv[j], acc[i][j], 0, 0, 0);
    }

#pragma unroll
    for (int i = 0; i < 4; ++i) {
        int rbase = mt * 128 + wm * 64 + 16 * i + quad * 4;
#pragma unroll
        for (int j = 0; j < 4; ++j) {
            int col = brow0 + 16 * j;
            float bj = biasv[j];
#pragma unroll
            for (int rg = 0; rg < 4; ++rg) {
                int r = rbase + rg;
                int b_i = r >> 9, t_i = r & 511;
                xu[((size_t)(t_i * 64 + b_i) << 12) + col] = f2bf(acc[i][j][rg] + bj);
            }
        }
    }
}

// ------------- recurrent scan: in-band phase-tagged h, NO flags/drain/poll -------------
// 128 blocks x 512 threads (8 waves), 1/CU. Group g=bx&3 owns batch rows
// [16g,16g+16); block cb=bx>>2 owns packed cols [128cb,128cb+128). V in
// registers (fp16, 128 VGPRs/lane). h stored as 15-bit fp16 (mantissa LSB
// dropped, rel err 2^-10) with bit0 = phase tag phi=(t>>1)&1. phi provably
// alternates between successive occupants (t, t+2) of a parity slot, so a
// tag match == freshness; the tag is ATOMIC with its value (same u16), so
// the load loop IS the poll -- no producer drain, no flag store, no
// serialized poll->load round trip. Overwrite safety without flags: block B
// publishes h_{t+2} only after completing step t+1's reads, which required
// fresh phi_{t+1} tags from ALL producers (B reads all 1024 cols); a
// producer only publishes h_{t+1} after its step-t barrier, i.e. after all
// its waves finished reading h_t. First-use + re-run staleness: slot0
// memset 0x00 (t=2 expects phi=1), slot1 memset 0xFF (t=1 expects phi=0).
// Split-K partials via double-buffered zs[2][8][16][132]: one barrier/step.
__global__ void __launch_bounds__(512, 2) lstm_rec_kernel(const u16* __restrict__ xu,
                                                          const u16* __restrict__ VT,
                                                          u16* hpl,
                                                          float* __restrict__ out) {
    __shared__ float zs[2][8][16][132];           // 135,168 B

    int bx = blockIdx.x;
    int g  = bx & 3;
    int cb = bx >> 2;                             // 0..31
    int tid = threadIdx.x;
    int lane = tid & 63, wv = tid >> 6;           // wv 0..7
    int l15 = lane & 15, quad = lane >> 4;
    int r  = tid >> 5;                            // batch row within group, 0..15
    int hc = tid & 31;                            // h-col within block, 0..31

    // ---- V fragments in registers (one-time load, 128 VGPRs, fp16) ----
    f16x8 vfrag[8][4];
    {
        const u16* vb = VT + ((size_t)(cb * 128 + l15) * 1024) + wv * 128 + quad * 8;
#pragma unroll
        for (int nt = 0; nt < 8; ++nt)
#pragma unroll
            for (int j = 0; j < 4; ++j)
                vfrag[nt][j] = *(const f16x8*)(vb + (size_t)nt * 16 * 1024 + j * 32);
    }

    float c = 0.f;
    float h = 0.f;

    uint2 xraw = *(const uint2*)(xu + ((size_t)(g * 16 + r) << 12) + cb * 128 + hc * 4);

    for (int t = 0; t < 512; ++t) {
        f32x4 acc[8];
#pragma unroll
        for (int nt = 0; nt < 8; ++nt) acc[nt] = f32x4{0.f, 0.f, 0.f, 0.f};

        if (t) {
            u32 phiRep = ((t >> 1) & 1) ? 0x00010001u : 0u;
            const u16* hB = hpl + (((size_t)(t & 1) * 4 + g) * 16 + l15) * 1024
                          + wv * 128 + quad * 8;
            u32x4 hv[4];
            // load-and-check loop: the load IS the poll. Tags are in-band
            // (atomic with values), so a full tag match proves every column
            // in the fragment is h_t -- no ordering assumptions needed.
            for (;;) {
#pragma unroll
                for (int j = 0; j < 4; ++j)
                    hv[j] = load16_uc(hB + j * 32);
                asm volatile("s_waitcnt vmcnt(0)"
                             : "+v"(hv[0]), "+v"(hv[1]), "+v"(hv[2]), "+v"(hv[3]));
                u32 bad = 0;
#pragma unroll
                for (int j = 0; j < 4; ++j)
#pragma unroll
                    for (int q = 0; q < 4; ++q)
                        bad |= (hv[j][q] ^ phiRep) & 0x00010001u;
                if (__ballot(bad == 0) == ~0ull) break;
            }
#pragma unroll
            for (int j = 0; j < 4; ++j) {
                union { u32x4 q; f16x8 v; } ah;
#pragma unroll
                for (int q = 0; q < 4; ++q) ah.q[q] = hv[j][q] & 0xFFFEFFFEu;
#pragma unroll
                for (int nt = 0; nt < 8; ++nt)
                    acc[nt] = __builtin_amdgcn_mfma_f32_16x16x32_f16(ah.v, vfrag[nt][j], acc[nt], 0, 0, 0);
            }
        }

        // split-K partial handoff (double-buffered; one barrier per step)
        float (*z)[16][132] = zs[t & 1];
#pragma unroll
        for (int nt = 0; nt < 8; ++nt)
#pragma unroll
            for (int rg = 0; rg < 4; ++rg)
                z[wv][quad * 4 + rg][nt * 16 + l15] = acc[nt][rg];
        __syncthreads();

        float4 s = {0.f, 0.f, 0.f, 0.f};
#pragma unroll
        for (int w = 0; w < 8; ++w) {
            float4 v = *(const float4*)&z[w][r][hc * 4];
            s.x += v.x; s.y += v.y; s.z += v.z; s.w += v.w;
        }
        float z0 = s.x + bf2f(xraw.x & 0xFFFFu);
        float z1 = s.y + bf2f(xraw.x >> 16);
        float z2 = s.z + bf2f(xraw.y & 0xFFFFu);
        float z3 = s.w + bf2f(xraw.y >> 16);

        float it_ = fast_sigmoid(z0);
        float ft_ = fast_sigmoid(z1);
        float gt_ = fast_tanh(z2);
        float ot_ = fast_tanh(z3);   // reference uses tanh for output gate
        c = ft_ * c + it_ * gt_;
        h = ot_ * fast_tanh(c);

        if (t == 511) break;     // final h never read back

        // publish h_{t+1}: 15-bit fp16 + phase tag bit. No drain, no flag.
        u32 h16 = (u32)f2h(h);
        u16 enc = (u16)(((h16 + 1u) & 0xFFFEu) | (u32)(((t + 1) >> 1) & 1));
        size_t sidx = (((size_t)((t + 1) & 1) * 4 + g) * 16 + r) * 1024 + cb * 32 + hc;
        __hip_atomic_store(hpl + sidx, enc, __ATOMIC_RELAXED,
                           __HIP_MEMORY_SCOPE_AGENT);

        // prefetch next xu (hides under the next load-check loop)
        xraw = *(const uint2*)(xu + ((size_t)((t + 1) * 64 + g * 16 + r) << 12) + cb * 128 + hc * 4);
    }

    out[(size_t)(g * 16 + r) * 1024 + cb * 32 + hc] = h;
}

extern "C" void kernel_launch(void* const* d_in, const int* in_sizes, int n_in,
                              void* d_out, int out_size, void* d_ws, size_t ws_size,
                              hipStream_t stream) {
    char* ws = (char*)d_ws;
    const float* x = (const float*)d_in[0];
    const float *U[4], *V[4], *b[4];
    for (int g = 0; g < 4; ++g) {
        U[g] = (const float*)d_in[1 + 3 * g];
        V[g] = (const float*)d_in[2 + 3 * g];
        b[g] = (const float*)d_in[3 + 3 * g];
    }
    u16*   xu = (u16*)(ws + XU_OFF);
    u16*   xb = (u16*)(ws + XB_OFF);
    u16*   UT = (u16*)(ws + UT_OFF);
    u16*   VT = (u16*)(ws + VT_OFF);
    float* bp = (float*)(ws + BP_OFF);
    u16*   hpl = (u16*)(ws + HHI_OFF);
    float* out = (float*)d_out;

    // Init h parity slots so their FIRST expected phase tag mismatches any
    // stale content (incl. previous-run leftovers): slot0 first read at t=2
    // expects phi=1 -> init bit0=0 (0x00); slot1 first read at t=1 expects
    // phi=0 -> init bit0=1 (0xFF).
    hipMemsetAsync(ws + HHI_OFF, 0x00, HT_HALF, stream);
    hipMemsetAsync(ws + HHI_OFF + HT_HALF, 0xFF, HT_HALF, stream);

    cvt_x_kernel<<<4096, 256, 0, stream>>>((const float4*)x, (uint2*)xb);
    repack_kernel<<<2048, 256, 0, stream>>>(U[0], U[1], U[2], U[3],
                                            V[0], V[1], V[2], V[3], UT, VT);
    bias_kernel<<<16, 256, 0, stream>>>(b[0], b[1], b[2], b[3], bp);
    gemm_xu_kernel<<<8192, 256, 0, stream>>>(xb, UT, bp, xu);

    void* args[] = {(void*)&xu, (void*)&VT, (void*)&hpl, (void*)&out};
    hipLaunchCooperativeKernel((const void*)lstm_rec_kernel, dim3(128), dim3(512),
                               args, 0, stream);
}

// Round 5
// 2222.103 us; speedup vs baseline: 1.5202x; 1.5202x over previous
//
#include <hip/hip_runtime.h>

using u16 = unsigned short;
using u32 = unsigned int;
using u64 = unsigned long long;
using bf16x8 = __attribute__((ext_vector_type(8))) short;
using f16x8  = __attribute__((ext_vector_type(8))) _Float16;
using f32x4  = __attribute__((ext_vector_type(4))) float;
using u32x4  = __attribute__((ext_vector_type(4))) unsigned int;

// ---------------- workspace layout (bytes) ----------------
static constexpr size_t XU_OFF = 0;
static constexpr size_t XU_BYTES = (size_t)512 * 64 * 4096 * 2;      // 256 MiB
static constexpr size_t XB_OFF = XU_OFF + XU_BYTES;
static constexpr size_t XB_BYTES = (size_t)64 * 512 * 1024 * 2;      // 64 MiB
static constexpr size_t UT_OFF = XB_OFF + XB_BYTES;
static constexpr size_t WT_BYTES = (size_t)4096 * 1024 * 2;          // 8 MiB
static constexpr size_t VT_OFF = UT_OFF + WT_BYTES;
static constexpr size_t BP_OFF = VT_OFF + WT_BYTES;
static constexpr size_t BP_BYTES = 4096 * 4;
// h plane: [2 parity][4 group][16 row][1024 col] u16 (fp16)
static constexpr size_t HT_PLANE = (size_t)2 * 4 * 16 * 1024 * 2;    // 256 KiB
static constexpr size_t HHI_OFF = BP_OFF + BP_BYTES;
static constexpr size_t HLO_OFF = HHI_OFF + HT_PLANE;                // unused (layout keep)
static constexpr size_t FLAG_OFF = HLO_OFF + HT_PLANE;
static constexpr size_t FLAG_BYTES = 4096;                           // flags[g*64+cb], cb<32 used

__device__ __forceinline__ float bf2f(u32 u) {
    return __uint_as_float(u << 16);
}
__device__ __forceinline__ u16 f2bf(float f) {
    u32 u = __float_as_uint(f);
    u32 r = (u + 0x7FFFu + ((u >> 16) & 1u)) >> 16;
    return (u16)r;
}
__device__ __forceinline__ u16 f2h(float f) {
    _Float16 x = (_Float16)f;                     // RTN
    union { _Float16 h; u16 u; } cv;
    cv.h = x;
    return cv.u;
}

// fast gates: v_exp + v_rcp (err ~1e-7, far below bf16 pipeline noise)
__device__ __forceinline__ float fast_sigmoid(float x) {
    return __builtin_amdgcn_rcpf(1.f + __expf(-x));
}
__device__ __forceinline__ float fast_tanh(float x) {
    return 1.f - 2.f * __builtin_amdgcn_rcpf(1.f + __expf(2.f * x));
}

// 16B cache-bypassing load (full-64B-line MALL requests)
__device__ __forceinline__ u32x4 load16_uc(const u16* p) {
    u32x4 v;
    asm volatile("global_load_dwordx4 %0, %1, off sc0 sc1"
                 : "=v"(v)
                 : "v"(p));
    return v;
}

// counted wait for h load j (4 loads issued; xu prefetch may be outstanding
// and is OLDER, so vmcnt(3-j) drains it first -- oldest-first is safe).
__device__ __forceinline__ void wait_vm4(int j, u32x4& a) {
    switch (j) {
    case 0:  asm volatile("s_waitcnt vmcnt(3)" : "+v"(a)); break;
    case 1:  asm volatile("s_waitcnt vmcnt(2)" : "+v"(a)); break;
    case 2:  asm volatile("s_waitcnt vmcnt(1)" : "+v"(a)); break;
    default: asm volatile("s_waitcnt vmcnt(0)" : "+v"(a)); break;
    }
}

// async global->LDS, 16B per lane (wave-uniform LDS base + lane*16)
__device__ __forceinline__ void gld16(const u16* g, u16* l) {
    __builtin_amdgcn_global_load_lds((const __attribute__((address_space(1))) void*)g,
                                     (__attribute__((address_space(3))) void*)l,
                                     16, 0, 0);
}

// ------------- x fp32 -> bf16 -------------
__global__ void cvt_x_kernel(const float4* __restrict__ x, uint2* __restrict__ xb) {
    int i = blockIdx.x * 256 + threadIdx.x;
#pragma unroll
    for (int k = 0; k < 8; ++k) {
        int idx = i + k * 1048576;
        float4 v = x[idx];
        uint2 o;
        o.x = (u32)f2bf(v.x) | ((u32)f2bf(v.y) << 16);
        o.y = (u32)f2bf(v.z) | ((u32)f2bf(v.w) << 16);
        xb[idx] = o;
    }
}

// ------------- repack: U fp32->bf16, V fp32->fp16; K-contiguous, gate-interleaved columns -------------
__global__ void repack_kernel(const float* U0, const float* U1, const float* U2, const float* U3,
                              const float* V0, const float* V1, const float* V2, const float* V3,
                              u16* UT, u16* VT) {
    __shared__ u16 tile[64][65];
    int bx  = blockIdx.x;
    int mat = bx >> 8;
    int rem = bx & 255;
    int tf = rem >> 4, th = rem & 15;
    int f0 = tf * 64, h0 = th * 64;
    const float* srcs[8] = {U0, U1, U2, U3, V0, V1, V2, V3};
    const float* s = srcs[mat];
    u16* d = (mat < 4) ? UT : VT;
    bool isU = (mat < 4);
    int g = mat & 3;
    int c = threadIdx.x & 63;
    int r = threadIdx.x >> 6;
#pragma unroll
    for (int i = 0; i < 16; ++i) {
        int fr = r + i * 4;
        float v = s[(size_t)(f0 + fr) * 1024 + h0 + c];
        tile[fr][c] = isU ? f2bf(v) : f2h(v);
    }
    __syncthreads();
#pragma unroll
    for (int i = 0; i < 16; ++i) {
        int hcl = r + i * 4;
        d[(size_t)((h0 + hcl) * 4 + g) * 1024 + f0 + c] = tile[c][hcl];
    }
}

// ------------- bias pack -------------
__global__ void bias_kernel(const float* b0, const float* b1, const float* b2, const float* b3,
                            float* bp) {
    int n = blockIdx.x * 256 + threadIdx.x;
    int g = n & 3, hc = n >> 2;
    const float* bs[4] = {b0, b1, b2, b3};
    bp[n] = bs[g][hc];
}

// ------------- xU GEMM: m97 structure (128x128 tile, BK=32, global_load_lds) -------------
// Was direct-global (no LDS, latency-exposed, ~250 TF). Now: LDS-staged via
// async global_load_lds width=16 (2 insts per 8KB tile), 2-barrier K-loop --
// the verified ~900 TF structure. Fragment semantics (A-row/B-row, k=quad*8)
// identical to previous version, so the verified scatter epilogue is unchanged.
// XCD-chunked swizzle kept: chunk spans all 32 nt -> UT (8MB) L2-resident/XCD.
__global__ void __launch_bounds__(256) gemm_xu_kernel(const u16* __restrict__ xb,
                                                      const u16* __restrict__ UT,
                                                      const float* __restrict__ bp,
                                                      u16* __restrict__ xu) {
    __shared__ u16 As[128 * 32];                  // 8 KB, [row][k] row-major
    __shared__ u16 Bs[128 * 32];                  // 8 KB

    int bx0 = blockIdx.x;
    int bx = (bx0 & 7) * 1024 + (bx0 >> 3);       // bijective (8192 % 8 == 0)
    int nt = bx & 31, mt = bx >> 5;
    int tid = threadIdx.x;
    int lane = tid & 63, wv = tid >> 6;
    int wm = wv & 1, wn = wv >> 1;
    int l15 = lane & 15, quad = lane >> 4;

    // staging addressing: id in [0,512): row=id>>2, k8=(id&3)*8; lane 16B.
    // LDS elem offset id*8 == row*32 + k8  (row-major [128][32])  -- linear,
    // matching the wave-uniform-base + lane*16 hardware pattern.
    int idr = tid >> 2, idk = (tid & 3) * 8;
    const u16* aSrc0 = xb + (size_t)(mt * 128 + idr) * 1024 + idk;
    const u16* aSrc1 = aSrc0 + (size_t)64 * 1024;
    const u16* bSrc0 = UT + (size_t)(nt * 128 + idr) * 1024 + idk;
    const u16* bSrc1 = bSrc0 + (size_t)64 * 1024;
    u16* aDst0 = As + (size_t)tid * 8;
    u16* aDst1 = As + (size_t)(tid + 256) * 8;
    u16* bDst0 = Bs + (size_t)tid * 8;
    u16* bDst1 = Bs + (size_t)(tid + 256) * 8;

    int arow = wm * 64 + l15;
    int brow = wn * 64 + l15;
    int brow0 = nt * 128 + brow;

    f32x4 acc[4][4];
#pragma unroll
    for (int i = 0; i < 4; ++i)
#pragma unroll
        for (int j = 0; j < 4; ++j) acc[i][j] = f32x4{0.f, 0.f, 0.f, 0.f};

    float biasv[4];
#pragma unroll
    for (int j = 0; j < 4; ++j) biasv[j] = bp[brow0 + 16 * j];

    for (int k0 = 0; k0 < 1024; k0 += 32) {
        gld16(aSrc0 + k0, aDst0);
        gld16(aSrc1 + k0, aDst1);
        gld16(bSrc0 + k0, bDst0);
        gld16(bSrc1 + k0, bDst1);
        __syncthreads();                          // compiler drains vmcnt before barrier

        bf16x8 af[4], bfv[4];
#pragma unroll
        for (int i = 0; i < 4; ++i)
            af[i] = *(const bf16x8*)(As + (size_t)(arow + i * 16) * 32 + quad * 8);
#pragma unroll
        for (int j = 0; j < 4; ++j)
            bfv[j] = *(const bf16x8*)(Bs + (size_t)(brow + j * 16) * 32 + quad * 8);
#pragma unroll
        for (int i = 0; i < 4; ++i)
#pragma unroll
            for (int j = 0; j < 4; ++j)
                acc[i][j] = __builtin_amdgcn_mfma_f32_16x16x32_bf16(af[i], bfv[j], acc[i][j], 0, 0, 0);
        __syncthreads();                          // protect LDS before next stage
    }

#pragma unroll
    for (int i = 0; i < 4; ++i) {
        int rbase = mt * 128 + wm * 64 + 16 * i + quad * 4;
#pragma unroll
        for (int j = 0; j < 4; ++j) {
            int col = brow0 + 16 * j;
            float bj = biasv[j];
#pragma unroll
            for (int rg = 0; rg < 4; ++rg) {
                int r = rbase + rg;
                int b_i = r >> 9, t_i = r & 511;
                xu[((size_t)(t_i * 64 + b_i) << 12) + col] = f2bf(acc[i][j][rg] + bj);
            }
        }
    }
}

// ------------- recurrent scan: fp16 single-plane h, V-in-registers (round-3 proven) -------------
// 128 blocks x 512 threads (8 waves), 1/CU. Group g=bx&3 owns batch rows
// [16g,16g+16); block cb=bx>>2 owns packed cols [128cb,128cb+128). V in
// registers (fp16, 128 VGPRs/lane, fixed across steps). h is one fp16 plane.
// Wave wv owns K-chunk [128wv,128wv+128): polls its 4 producers [4wv,4wv+4);
// 8-wave union covers all 32 group blocks (parity-slot safety). Split-K via
// LDS zs[8][16][132]. NOTE round-4 lesson: in-band tag + load-retry regressed
// (spin payload 64B/lane floods MALL; flag poll spin is 4B/lane) -- keep flags.
__global__ void __launch_bounds__(512, 2) lstm_rec_kernel(const u16* __restrict__ xu,
                                                          const u16* __restrict__ VT,
                                                          u16* hhi,
                                                          u16* hlo,   // unused
                                                          u32* flags,
                                                          float* __restrict__ out) {
    __shared__ float zs[8][16][132];              // 67,584 B

    int bx = blockIdx.x;
    int g  = bx & 3;
    int cb = bx >> 2;                             // 0..31
    int tid = threadIdx.x;
    int lane = tid & 63, wv = tid >> 6;           // wv 0..7
    int l15 = lane & 15, quad = lane >> 4;
    int r  = tid >> 5;                            // batch row within group, 0..15
    int hc = tid & 31;                            // h-col within block, 0..31

    // ---- V fragments in registers (one-time load, 128 VGPRs, fp16) ----
    f16x8 vfrag[8][4];
    {
        const u16* vb = VT + ((size_t)(cb * 128 + l15) * 1024) + wv * 128 + quad * 8;
#pragma unroll
        for (int nt = 0; nt < 8; ++nt)
#pragma unroll
            for (int j = 0; j < 4; ++j)
                vfrag[nt][j] = *(const f16x8*)(vb + (size_t)nt * 16 * 1024 + j * 32);
    }

    u32* gflags = flags + g * 64;
    int myp = 4 * wv + (lane & 3);                // producer polled by this lane

    float c = 0.f;
    float h = 0.f;

    uint2 xraw = *(const uint2*)(xu + ((size_t)(g * 16 + r) << 12) + cb * 128 + hc * 4);

    for (int t = 0; t < 512; ++t) {
        f32x4 acc[8];
#pragma unroll
        for (int nt = 0; nt < 8; ++nt) acc[nt] = f32x4{0.f, 0.f, 0.f, 0.f};

        if (t) {
            // 1) poll this wave's 4 producers (lanes replicate x16; ballot all-set)
            for (;;) {
                u32 f = __hip_atomic_load(gflags + myp, __ATOMIC_RELAXED,
                                          __HIP_MEMORY_SCOPE_AGENT);
                if (__ballot(f >= (u32)t) == ~0ull) break;
                __builtin_amdgcn_s_sleep(1);
            }
            asm volatile("" ::: "memory");        // keep h loads below the poll

            // 2) stream h fragments: 4x16B uncached loads, full-line MALL reads
            const u16* hB = hhi + (((size_t)(t & 1) * 4 + g) * 16 + l15) * 1024
                          + wv * 128 + quad * 8;
            u32x4 hv[4];
#pragma unroll
            for (int j = 0; j < 4; ++j)
                hv[j] = load16_uc(hB + j * 32);
#pragma unroll
            for (int j = 0; j < 4; ++j) {
                wait_vm4(j, hv[j]);               // counted wait, ties block MFMA hoist
                union { u32x4 q; f16x8 v; } ah;
                ah.q = hv[j];
#pragma unroll
                for (int nt = 0; nt < 8; ++nt)
                    acc[nt] = __builtin_amdgcn_mfma_f32_16x16x32_f16(ah.v, vfrag[nt][j], acc[nt], 0, 0, 0);
            }
        }

        // 3) split-K partial handoff: C layout col=l15, row=quad*4+rg
#pragma unroll
        for (int nt = 0; nt < 8; ++nt)
#pragma unroll
            for (int rg = 0; rg < 4; ++rg)
                zs[wv][quad * 4 + rg][nt * 16 + l15] = acc[nt][rg];
        __syncthreads();

        float4 s = {0.f, 0.f, 0.f, 0.f};
#pragma unroll
        for (int w = 0; w < 8; ++w) {
            float4 v = *(const float4*)&zs[w][r][hc * 4];
            s.x += v.x; s.y += v.y; s.z += v.z; s.w += v.w;
        }
        float z0 = s.x + bf2f(xraw.x & 0xFFFFu);
        float z1 = s.y + bf2f(xraw.x >> 16);
        float z2 = s.z + bf2f(xraw.y & 0xFFFFu);
        float z3 = s.w + bf2f(xraw.y >> 16);

        float it_ = fast_sigmoid(z0);
        float ft_ = fast_sigmoid(z1);
        float gt_ = fast_tanh(z2);
        float ot_ = fast_tanh(z3);   // reference uses tanh for output gate
        c = ft_ * c + it_ * gt_;
        h = ot_ * fast_tanh(c);

        if (t == 511) break;     // final h never read back

        // 4) publish h (single fp16 write-through) + drain (stores only) + flag
        size_t sidx = (((size_t)((t + 1) & 1) * 4 + g) * 16 + r) * 1024 + cb * 32 + hc;
        __hip_atomic_store(hhi + sidx, f2h(h), __ATOMIC_RELAXED,
                           __HIP_MEMORY_SCOPE_AGENT);
        asm volatile("s_waitcnt vmcnt(0)" ::: "memory");
        __syncthreads();          // also protects zs reuse next iteration
        if (tid == 0)
            __hip_atomic_store(gflags + cb, (u32)(t + 1), __ATOMIC_RELAXED,
                               __HIP_MEMORY_SCOPE_AGENT);

        // 5) prefetch next xu AFTER the flag: its HBM-miss latency hides under
        //    the next poll window instead of sitting in the publish drain.
        xraw = *(const uint2*)(xu + ((size_t)((t + 1) * 64 + g * 16 + r) << 12) + cb * 128 + hc * 4);
    }

    out[(size_t)(g * 16 + r) * 1024 + cb * 32 + hc] = h;
}

extern "C" void kernel_launch(void* const* d_in, const int* in_sizes, int n_in,
                              void* d_out, int out_size, void* d_ws, size_t ws_size,
                              hipStream_t stream) {
    char* ws = (char*)d_ws;
    const float* x = (const float*)d_in[0];
    const float *U[4], *V[4], *b[4];
    for (int g = 0; g < 4; ++g) {
        U[g] = (const float*)d_in[1 + 3 * g];
        V[g] = (const float*)d_in[2 + 3 * g];
        b[g] = (const float*)d_in[3 + 3 * g];
    }
    u16*   xu = (u16*)(ws + XU_OFF);
    u16*   xb = (u16*)(ws + XB_OFF);
    u16*   UT = (u16*)(ws + UT_OFF);
    u16*   VT = (u16*)(ws + VT_OFF);
    float* bp = (float*)(ws + BP_OFF);
    u16*   hhi = (u16*)(ws + HHI_OFF);
    u16*   hlo = (u16*)(ws + HLO_OFF);
    u32*   flags = (u32*)(ws + FLAG_OFF);
    float* out = (float*)d_out;

    // flags must start at 0 (0xAA poison would satisfy any poll immediately)
    hipMemsetAsync(ws + FLAG_OFF, 0, FLAG_BYTES, stream);

    cvt_x_kernel<<<4096, 256, 0, stream>>>((const float4*)x, (uint2*)xb);
    repack_kernel<<<2048, 256, 0, stream>>>(U[0], U[1], U[2], U[3],
                                            V[0], V[1], V[2], V[3], UT, VT);
    bias_kernel<<<16, 256, 0, stream>>>(b[0], b[1], b[2], b[3], bp);
    gemm_xu_kernel<<<8192, 256, 0, stream>>>(xb, UT, bp, xu);

    void* args[] = {(void*)&xu, (void*)&VT, (void*)&hhi, (void*)&hlo,
                    (void*)&flags, (void*)&out};
    hipLaunchCooperativeKernel((const void*)lstm_rec_kernel, dim3(128), dim3(512),
                               args, 0, stream);
}

// Round 6
// 2192.310 us; speedup vs baseline: 1.5409x; 1.0136x over previous
//
#include <hip/hip_runtime.h>

using u16 = unsigned short;
using u32 = unsigned int;
using u64 = unsigned long long;
using bf16x8 = __attribute__((ext_vector_type(8))) short;
using f16x8  = __attribute__((ext_vector_type(8))) _Float16;
using f32x4  = __attribute__((ext_vector_type(4))) float;
using u32x4  = __attribute__((ext_vector_type(4))) unsigned int;

// ---------------- workspace layout (bytes) ----------------
static constexpr size_t XU_OFF = 0;
static constexpr size_t XU_BYTES = (size_t)512 * 64 * 4096 * 2;      // 256 MiB
static constexpr size_t XB_OFF = XU_OFF + XU_BYTES;
static constexpr size_t XB_BYTES = (size_t)64 * 512 * 1024 * 2;      // 64 MiB
static constexpr size_t UT_OFF = XB_OFF + XB_BYTES;
static constexpr size_t WT_BYTES = (size_t)4096 * 1024 * 2;          // 8 MiB
static constexpr size_t VT_OFF = UT_OFF + WT_BYTES;
static constexpr size_t BP_OFF = VT_OFF + WT_BYTES;
static constexpr size_t BP_BYTES = 4096 * 4;
// h plane: [2 parity][4 group][16 row][1024 col] u16 (fp16)
static constexpr size_t HT_PLANE = (size_t)2 * 4 * 16 * 1024 * 2;    // 256 KiB
static constexpr size_t HHI_OFF = BP_OFF + BP_BYTES;
static constexpr size_t FLAG_OFF = HHI_OFF + HT_PLANE;
static constexpr size_t FLAG_BYTES = 4096;   // flags[g*64+cb] (1KB) + chunk cnt[4] @ +2048

__device__ __forceinline__ float bf2f(u32 u) {
    return __uint_as_float(u << 16);
}
__device__ __forceinline__ u16 f2bf(float f) {
    u32 u = __float_as_uint(f);
    u32 r = (u + 0x7FFFu + ((u >> 16) & 1u)) >> 16;
    return (u16)r;
}
__device__ __forceinline__ u16 f2h(float f) {
    _Float16 x = (_Float16)f;                     // RTN
    union { _Float16 h; u16 u; } cv;
    cv.h = x;
    return cv.u;
}

// fast gates: v_exp + v_rcp (err ~1e-7, far below bf16 pipeline noise)
__device__ __forceinline__ float fast_sigmoid(float x) {
    return __builtin_amdgcn_rcpf(1.f + __expf(-x));
}
__device__ __forceinline__ float fast_tanh(float x) {
    return 1.f - 2.f * __builtin_amdgcn_rcpf(1.f + __expf(2.f * x));
}

// 16B cache-bypassing load (full-64B-line MALL requests)
__device__ __forceinline__ u32x4 load16_uc(const u16* p) {
    u32x4 v;
    asm volatile("global_load_dwordx4 %0, %1, off sc0 sc1"
                 : "=v"(v)
                 : "v"(p));
    return v;
}

// 16B write-through store (MALL-visible: required for cross-XCD produce/consume
// of xu inside ONE kernel -- plain cached stores would leave dirty lines in the
// producer XCD's L2, invisible to consumer XCDs).
__device__ __forceinline__ void store16_wt(u16* p, u32x4 v) {
    asm volatile("global_store_dwordx4 %0, %1, off sc0 sc1"
                 :: "v"(p), "v"(v) : "memory");
}

// counted wait for h load j (4 loads issued; xu prefetch may be outstanding
// and is OLDER, so vmcnt(3-j) drains it first -- oldest-first is safe).
__device__ __forceinline__ void wait_vm4(int j, u32x4& a) {
    switch (j) {
    case 0:  asm volatile("s_waitcnt vmcnt(3)" : "+v"(a)); break;
    case 1:  asm volatile("s_waitcnt vmcnt(2)" : "+v"(a)); break;
    case 2:  asm volatile("s_waitcnt vmcnt(1)" : "+v"(a)); break;
    default: asm volatile("s_waitcnt vmcnt(0)" : "+v"(a)); break;
    }
}

// async global->LDS, 16B per lane (wave-uniform LDS base + lane*16)
__device__ __forceinline__ void gld16(const u16* g, u16* l) {
    __builtin_amdgcn_global_load_lds((const __attribute__((address_space(1))) void*)g,
                                     (__attribute__((address_space(3))) void*)l,
                                     16, 0, 0);
}

// xu t-chunk readiness gate (2048 tiles per chunk)
__device__ __forceinline__ void wait_chunk(const u32* cnt, int c) {
    for (;;) {
        u32 v = __hip_atomic_load(cnt + c, __ATOMIC_RELAXED, __HIP_MEMORY_SCOPE_AGENT);
        if (v >= 2048u) break;
        __builtin_amdgcn_s_sleep(8);
    }
    asm volatile("" ::: "memory");   // keep xu loads below the gate
}

// ------------- x fp32 -> bf16 -------------
__global__ void cvt_x_kernel(const float4* __restrict__ x, uint2* __restrict__ xb) {
    int i = blockIdx.x * 256 + threadIdx.x;
#pragma unroll
    for (int k = 0; k < 8; ++k) {
        int idx = i + k * 1048576;
        float4 v = x[idx];
        uint2 o;
        o.x = (u32)f2bf(v.x) | ((u32)f2bf(v.y) << 16);
        o.y = (u32)f2bf(v.z) | ((u32)f2bf(v.w) << 16);
        xb[idx] = o;
    }
}

// ------------- repack: U fp32->bf16, V fp32->fp16; K-contiguous, gate-interleaved columns -------------
__global__ void repack_kernel(const float* U0, const float* U1, const float* U2, const float* U3,
                              const float* V0, const float* V1, const float* V2, const float* V3,
                              u16* UT, u16* VT) {
    __shared__ u16 tile[64][65];
    int bx  = blockIdx.x;
    int mat = bx >> 8;
    int rem = bx & 255;
    int tf = rem >> 4, th = rem & 15;
    int f0 = tf * 64, h0 = th * 64;
    const float* srcs[8] = {U0, U1, U2, U3, V0, V1, V2, V3};
    const float* s = srcs[mat];
    u16* d = (mat < 4) ? UT : VT;
    bool isU = (mat < 4);
    int g = mat & 3;
    int c = threadIdx.x & 63;
    int r = threadIdx.x >> 6;
#pragma unroll
    for (int i = 0; i < 16; ++i) {
        int fr = r + i * 4;
        float v = s[(size_t)(f0 + fr) * 1024 + h0 + c];
        tile[fr][c] = isU ? f2bf(v) : f2h(v);
    }
    __syncthreads();
#pragma unroll
    for (int i = 0; i < 16; ++i) {
        int hcl = r + i * 4;
        d[(size_t)((h0 + hcl) * 4 + g) * 1024 + f0 + c] = tile[c][hcl];
    }
}

// ------------- bias pack -------------
__global__ void bias_kernel(const float* b0, const float* b1, const float* b2, const float* b3,
                            float* bp) {
    int n = blockIdx.x * 256 + threadIdx.x;
    int g = n & 3, hc = n >> 2;
    const float* bs[4] = {b0, b1, b2, b3};
    bp[n] = bs[g][hc];
}

// ------------- one 128x128 xU GEMM tile, 8 waves (512 threads) -------------
// Chunk-ordered tile index tau: tc=tau>>11 (t-chunk), b=(tau&2047)>>5, nt=tau&31,
// mt=b*4+tc. LDS-staged (one gld16 per matrix per K-step), MFMA 4x2 per wave.
// Epilogue: acc -> LDS C-tile (bf16+bias) -> coalesced 256B-per-16-lane
// write-through stores -> vmcnt drain -> barrier -> chunk counter bump.
__device__ __forceinline__ void gemm_tile(int tau,
        const u16* __restrict__ xb, const u16* __restrict__ UT,
        const float* __restrict__ bp, u16* __restrict__ xu,
        u16* As, u16* Bs, u16* Cs, u32* cnt) {
    int tc = tau >> 11, rem = tau & 2047;
    int b = rem >> 5, nt = rem & 31, mt = b * 4 + tc;
    int tid = threadIdx.x;
    int lane = tid & 63, wv = tid >> 6;
    int wm = wv >> 2, wn = wv & 3;                // 2 x 4 wave grid
    int l15 = lane & 15, quad = lane >> 4;

    // staging: 512 threads x 16B = 8KB = one full [128][32] tile per inst
    int idr = tid >> 2, idk = (tid & 3) * 8;
    const u16* aS = xb + (size_t)(mt * 128 + idr) * 1024 + idk;
    const u16* bS = UT + (size_t)(nt * 128 + idr) * 1024 + idk;
    u16* aD = As + (size_t)tid * 8;
    u16* bD = Bs + (size_t)tid * 8;

    f32x4 acc[4][2];
#pragma unroll
    for (int i = 0; i < 4; ++i)
#pragma unroll
        for (int j = 0; j < 2; ++j) acc[i][j] = f32x4{0.f, 0.f, 0.f, 0.f};

    float biasv[2];
#pragma unroll
    for (int j = 0; j < 2; ++j) biasv[j] = bp[nt * 128 + wn * 32 + j * 16 + l15];

    for (int k0 = 0; k0 < 1024; k0 += 32) {
        gld16(aS + k0, aD);
        gld16(bS + k0, bD);
        __syncthreads();                          // compiler drains vmcnt first
        bf16x8 af[4], bfv[2];
#pragma unroll
        for (int i = 0; i < 4; ++i)
            af[i] = *(const bf16x8*)(As + (size_t)(wm * 64 + i * 16 + l15) * 32 + quad * 8);
#pragma unroll
        for (int j = 0; j < 2; ++j)
            bfv[j] = *(const bf16x8*)(Bs + (size_t)(wn * 32 + j * 16 + l15) * 32 + quad * 8);
#pragma unroll
        for (int i = 0; i < 4; ++i)
#pragma unroll
            for (int j = 0; j < 2; ++j)
                acc[i][j] = __builtin_amdgcn_mfma_f32_16x16x32_bf16(af[i], bfv[j], acc[i][j], 0, 0, 0);
        __syncthreads();                          // protect LDS before next stage
    }

    // acc -> LDS C-tile (row-pad 136 u16 kills the 64-aligned bank repeat)
#pragma unroll
    for (int i = 0; i < 4; ++i)
#pragma unroll
        for (int j = 0; j < 2; ++j)
#pragma unroll
            for (int rg = 0; rg < 4; ++rg)
                Cs[(size_t)(wm * 64 + i * 16 + quad * 4 + rg) * 136 + wn * 32 + j * 16 + l15] =
                    f2bf(acc[i][j][rg] + biasv[j]);
    __syncthreads();

    // coalesced write-through: 16 lanes cover one 256B row-segment
#pragma unroll
    for (int p = 0; p < 4; ++p) {
        int id = p * 512 + tid;
        int row = id >> 4, q = id & 15;
        u32x4 v = *(const u32x4*)(Cs + (size_t)row * 136 + q * 8);
        int gr = mt * 128 + row;
        int t_i = gr & 511, b_i = gr >> 9;
        store16_wt(xu + (((size_t)(t_i * 64 + b_i)) << 12) + nt * 128 + q * 8, v);
    }
    asm volatile("s_waitcnt vmcnt(0)" ::: "memory");
    __syncthreads();                              // all waves' stores MALL-acked
    if (tid == 0)
        __hip_atomic_fetch_add(cnt + tc, 1u, __ATOMIC_RELAXED, __HIP_MEMORY_SCOPE_AGENT);
}

// ------------- fused kernel: xU GEMM overlapped with the recurrent scan -------------
// 256 blocks x 512 threads, 1/CU (118KB LDS). PHASE A: all blocks build xu
// t-chunk 0 (tiles 0..2047, contiguous 8/block) -- scan cannot start earlier
// anyway. Then blocks 0..127 run the round-5 scan (identical structure);
// blocks 128..255 build chunks 1..3 with stride-128 tile order so chunk c
// completes ~c*16 tile-times into phase B -- always ahead of the scan's need
// (~c*410us). Scan gates its xu prefetch on per-chunk counters (target 2048).
__global__ void __launch_bounds__(512, 2) lstm_fused_kernel(
        const u16* __restrict__ xb, const u16* __restrict__ UT,
        const float* __restrict__ bp, u16* __restrict__ xu,
        const u16* __restrict__ VT, u16* hhi, u32* flags, u32* cnt,
        float* __restrict__ out) {
    __shared__ u16 As[128 * 32];                  // 8 KB
    __shared__ u16 Bs[128 * 32];                  // 8 KB
    __shared__ u16 Cs[128 * 136];                 // 34 KB
    __shared__ float zs[8][16][132];              // 67.6 KB

    int bx = blockIdx.x;

    // ---- PHASE A: chunk 0 on the full GPU ----
    for (int p = 0; p < 8; ++p)
        gemm_tile(bx * 8 + p, xb, UT, bp, xu, As, Bs, Cs, cnt);

    if (bx >= 128) {
        // ---- PHASE B: chunks 1..3 on blocks 128..255 ----
        int gid = bx - 128;
        for (int p = 0; p < 48; ++p)
            gemm_tile(2048 + p * 128 + gid, xb, UT, bp, xu, As, Bs, Cs, cnt);
        return;
    }

    // ---- recurrent scan (round-5 proven structure) ----
    int g  = bx & 3;
    int cb = bx >> 2;                             // 0..31
    int tid = threadIdx.x;
    int lane = tid & 63, wv = tid >> 6;           // wv 0..7
    int l15 = lane & 15, quad = lane >> 4;
    int r  = tid >> 5;                            // batch row within group, 0..15
    int hc = tid & 31;                            // h-col within block, 0..31

    // V fragments in registers (fp16, 128 VGPRs/lane, fixed across steps)
    f16x8 vfrag[8][4];
    {
        const u16* vb = VT + ((size_t)(cb * 128 + l15) * 1024) + wv * 128 + quad * 8;
#pragma unroll
        for (int nt = 0; nt < 8; ++nt)
#pragma unroll
            for (int j = 0; j < 4; ++j)
                vfrag[nt][j] = *(const f16x8*)(vb + (size_t)nt * 16 * 1024 + j * 32);
    }

    u32* gflags = flags + g * 64;
    int myp = 4 * wv + (lane & 3);                // producer polled by this lane

    float c = 0.f;
    float h = 0.f;

    wait_chunk(cnt, 0);
    uint2 xraw = *(const uint2*)(xu + ((size_t)(g * 16 + r) << 12) + cb * 128 + hc * 4);

    for (int t = 0; t < 512; ++t) {
        f32x4 acc[8];
#pragma unroll
        for (int nt = 0; nt < 8; ++nt) acc[nt] = f32x4{0.f, 0.f, 0.f, 0.f};

        if (t) {
            // 1) poll this wave's 4 producers (lanes replicate x16; ballot all-set)
            for (;;) {
                u32 f = __hip_atomic_load(gflags + myp, __ATOMIC_RELAXED,
                                          __HIP_MEMORY_SCOPE_AGENT);
                if (__ballot(f >= (u32)t) == ~0ull) break;
                __builtin_amdgcn_s_sleep(1);
            }
            asm volatile("" ::: "memory");        // keep h loads below the poll

            // 2) stream h fragments: 4x16B uncached loads, full-line MALL reads
            const u16* hB = hhi + (((size_t)(t & 1) * 4 + g) * 16 + l15) * 1024
                          + wv * 128 + quad * 8;
            u32x4 hv[4];
#pragma unroll
            for (int j = 0; j < 4; ++j)
                hv[j] = load16_uc(hB + j * 32);
#pragma unroll
            for (int j = 0; j < 4; ++j) {
                wait_vm4(j, hv[j]);               // counted wait, ties block MFMA hoist
                union { u32x4 q; f16x8 v; } ah;
                ah.q = hv[j];
#pragma unroll
                for (int nt = 0; nt < 8; ++nt)
                    acc[nt] = __builtin_amdgcn_mfma_f32_16x16x32_f16(ah.v, vfrag[nt][j], acc[nt], 0, 0, 0);
            }
        }

        // 3) split-K partial handoff: C layout col=l15, row=quad*4+rg
#pragma unroll
        for (int nt = 0; nt < 8; ++nt)
#pragma unroll
            for (int rg = 0; rg < 4; ++rg)
                zs[wv][quad * 4 + rg][nt * 16 + l15] = acc[nt][rg];
        __syncthreads();

        float4 s = {0.f, 0.f, 0.f, 0.f};
#pragma unroll
        for (int w = 0; w < 8; ++w) {
            float4 v = *(const float4*)&zs[w][r][hc * 4];
            s.x += v.x; s.y += v.y; s.z += v.z; s.w += v.w;
        }
        float z0 = s.x + bf2f(xraw.x & 0xFFFFu);
        float z1 = s.y + bf2f(xraw.x >> 16);
        float z2 = s.z + bf2f(xraw.y & 0xFFFFu);
        float z3 = s.w + bf2f(xraw.y >> 16);

        float it_ = fast_sigmoid(z0);
        float ft_ = fast_sigmoid(z1);
        float gt_ = fast_tanh(z2);
        float ot_ = fast_tanh(z3);   // reference uses tanh for output gate
        c = ft_ * c + it_ * gt_;
        h = ot_ * fast_tanh(c);

        if (t == 511) break;     // final h never read back

        // 4) publish h (single fp16 write-through) + drain (stores only) + flag
        size_t sidx = (((size_t)((t + 1) & 1) * 4 + g) * 16 + r) * 1024 + cb * 32 + hc;
        __hip_atomic_store(hhi + sidx, f2h(h), __ATOMIC_RELAXED,
                           __HIP_MEMORY_SCOPE_AGENT);
        asm volatile("s_waitcnt vmcnt(0)" ::: "memory");
        __syncthreads();          // also protects zs reuse next iteration
        if (tid == 0)
            __hip_atomic_store(gflags + cb, (u32)(t + 1), __ATOMIC_RELAXED,
                               __HIP_MEMORY_SCOPE_AGENT);

        // 5) prefetch next xu AFTER the flag (chunk-gated every 128 steps;
        //    gate is after the flag store so it never extends the publish path)
        if (((t + 1) & 127) == 0) wait_chunk(cnt, (t + 1) >> 7);
        xraw = *(const uint2*)(xu + ((size_t)((t + 1) * 64 + g * 16 + r) << 12) + cb * 128 + hc * 4);
    }

    out[(size_t)(g * 16 + r) * 1024 + cb * 32 + hc] = h;
}

extern "C" void kernel_launch(void* const* d_in, const int* in_sizes, int n_in,
                              void* d_out, int out_size, void* d_ws, size_t ws_size,
                              hipStream_t stream) {
    char* ws = (char*)d_ws;
    const float* x = (const float*)d_in[0];
    const float *U[4], *V[4], *b[4];
    for (int g = 0; g < 4; ++g) {
        U[g] = (const float*)d_in[1 + 3 * g];
        V[g] = (const float*)d_in[2 + 3 * g];
        b[g] = (const float*)d_in[3 + 3 * g];
    }
    u16*   xu = (u16*)(ws + XU_OFF);
    u16*   xb = (u16*)(ws + XB_OFF);
    u16*   UT = (u16*)(ws + UT_OFF);
    u16*   VT = (u16*)(ws + VT_OFF);
    float* bp = (float*)(ws + BP_OFF);
    u16*   hhi = (u16*)(ws + HHI_OFF);
    u32*   flags = (u32*)(ws + FLAG_OFF);
    u32*   cnt = (u32*)(ws + FLAG_OFF + 2048);
    float* out = (float*)d_out;

    // flags + chunk counters must start at 0
    hipMemsetAsync(ws + FLAG_OFF, 0, FLAG_BYTES, stream);

    cvt_x_kernel<<<4096, 256, 0, stream>>>((const float4*)x, (uint2*)xb);
    repack_kernel<<<2048, 256, 0, stream>>>(U[0], U[1], U[2], U[3],
                                            V[0], V[1], V[2], V[3], UT, VT);
    bias_kernel<<<16, 256, 0, stream>>>(b[0], b[1], b[2], b[3], bp);

    void* args[] = {(void*)&xb, (void*)&UT, (void*)&bp, (void*)&xu,
                    (void*)&VT, (void*)&hhi, (void*)&flags, (void*)&cnt,
                    (void*)&out};
    hipLaunchCooperativeKernel((const void*)lstm_fused_kernel, dim3(256), dim3(512),
                               args, 0, stream);
}